// Round 1
// baseline (419.494 us; speedup 1.0000x reference)
//
#include <hip/hip_runtime.h>

#define TSEQ 2048
#define TBZ  32
#define TDIM 1024

typedef __attribute__((ext_vector_type(8))) short bf16x8;
typedef __attribute__((ext_vector_type(4))) float f32x4;

constexpr int BM = 128, BN = 128, BK = 32;
constexpr int LDSS = BK + 8;   // 40 bf16 = 80 B row stride (16B-aligned, breaks pow2 banks)

__device__ inline unsigned short f2bf(float f) {
    union { float f; unsigned int u; } v; v.f = f;
    unsigned int r = v.u + 0x7fffu + ((v.u >> 16) & 1u);   // RNE
    return (unsigned short)(r >> 16);
}

__global__ __launch_bounds__(256) void mapper_gemm(
    const float* __restrict__ x, const int* __restrict__ lang_ids,
    const float* __restrict__ W, const float* __restrict__ bias,
    float* __restrict__ out)
{
    const int bid = blockIdx.x;
    const int b   = bid >> 7;        // 128 tiles per batch column
    const int t   = bid & 127;
    const int mt  = t >> 3;          // 16 m-tiles
    const int nt  = t & 7;           // 8 n-tiles (fastest -> x-panel reuse)
    const int s0  = mt * BM;
    const int e0  = nt * BN;
    const int tid = threadIdx.x;

    const int lid    = lang_ids[b];
    const int gid    = 8 - lid;                       // DICT_LEN-1 - lang_ids
    const bool active = (gid >= 1) && (gid <= 8);
    int eb = gid - 1; eb = eb < 0 ? 0 : (eb > 7 ? 7 : eb);

    if (!active) {
        // pass-through: out[s, b, e0:e0+128] = x[s, b, e0:e0+128] for s in [s0, s0+128)
        const f32x4* xs = (const f32x4*)x;
        f32x4*       os = (f32x4*)out;
        const int rowstride4 = TBZ * TDIM / 4;        // 8192 float4 per s-row
        #pragma unroll
        for (int i = tid; i < (BM * BN) / 4; i += 256) {
            int r = i >> 5;                           // 32 float4 per 128-col row
            int c = i & 31;
            long idx = (long)(s0 + r) * rowstride4 + b * (TDIM / 4) + (e0 >> 2) + c;
            os[idx] = xs[idx];
        }
        return;
    }

    __shared__ unsigned short As[BM * LDSS];
    __shared__ unsigned short Bs[BN * LDSS];

    const float* __restrict__ Wb = W + (long)eb * TDIM * TDIM;

    const int lane = tid & 63;
    const int wave = tid >> 6;         // 4 waves
    const int wr   = wave >> 1;        // 2x2 wave grid, each wave 64x64 out
    const int wc   = wave & 1;

    f32x4 acc[4][4];
    #pragma unroll
    for (int m = 0; m < 4; ++m)
        #pragma unroll
        for (int n = 0; n < 4; ++n)
            acc[m][n] = (f32x4){0.f, 0.f, 0.f, 0.f};

    // staging decomposition: 256 threads cover 128 rows x 32 cols (f32) per tile
    const int rg = tid >> 3;           // 0..31 row group
    const int cg = tid & 7;            // 0..7  -> float4 col (cg*4)

    const int fr = lane & 15;          // fragment row/col within 16
    const int fo = (lane >> 4) * 8;    // fragment k-offset (8 bf16)

    for (int k0 = 0; k0 < TDIM; k0 += BK) {
        __syncthreads();               // protect LDS from previous iter's readers
        #pragma unroll
        for (int p = 0; p < 4; ++p) {
            const int r = rg + p * 32;
            f32x4 av = *(const f32x4*)(x  + (long)(s0 + r) * (TBZ * TDIM) + b * TDIM + k0 + cg * 4);
            f32x4 bv = *(const f32x4*)(Wb + (long)(e0 + r) * TDIM + k0 + cg * 4);
            unsigned int alo = (unsigned)f2bf(av.x) | ((unsigned)f2bf(av.y) << 16);
            unsigned int ahi = (unsigned)f2bf(av.z) | ((unsigned)f2bf(av.w) << 16);
            unsigned int blo = (unsigned)f2bf(bv.x) | ((unsigned)f2bf(bv.y) << 16);
            unsigned int bhi = (unsigned)f2bf(bv.z) | ((unsigned)f2bf(bv.w) << 16);
            *(uint2*)&As[r * LDSS + cg * 4] = make_uint2(alo, ahi);
            *(uint2*)&Bs[r * LDSS + cg * 4] = make_uint2(blo, bhi);
        }
        __syncthreads();

        bf16x8 af[4], bf[4];
        #pragma unroll
        for (int m = 0; m < 4; ++m)
            af[m] = *(const bf16x8*)&As[(wr * 64 + m * 16 + fr) * LDSS + fo];
        #pragma unroll
        for (int n = 0; n < 4; ++n)
            bf[n] = *(const bf16x8*)&Bs[(wc * 64 + n * 16 + fr) * LDSS + fo];
        #pragma unroll
        for (int m = 0; m < 4; ++m)
            #pragma unroll
            for (int n = 0; n < 4; ++n)
                acc[m][n] = __builtin_amdgcn_mfma_f32_16x16x32_bf16(af[m], bf[n], acc[m][n], 0, 0, 0);
    }

    // epilogue: C/D layout col=lane&15, row=(lane>>4)*4+j  [verified m89/m91]
    const int cr = lane >> 4;
    const int cc = lane & 15;
    #pragma unroll
    for (int n = 0; n < 4; ++n) {
        const int e  = e0 + wc * 64 + n * 16 + cc;
        const float bv = bias[eb * TDIM + e];
        #pragma unroll
        for (int m = 0; m < 4; ++m) {
            #pragma unroll
            for (int j = 0; j < 4; ++j) {
                const int s = s0 + wr * 64 + m * 16 + cr * 4 + j;
                out[(long)s * (TBZ * TDIM) + b * TDIM + e] = acc[m][n][j] + bv;
            }
        }
    }
}

extern "C" void kernel_launch(void* const* d_in, const int* in_sizes, int n_in,
                              void* d_out, int out_size, void* d_ws, size_t ws_size,
                              hipStream_t stream) {
    const float* x        = (const float*)d_in[0];
    const int*   lang_ids = (const int*)d_in[1];
    const float* W        = (const float*)d_in[2];
    const float* bias     = (const float*)d_in[3];
    float*       out      = (float*)d_out;

    const int grid = TBZ * (TSEQ / BM) * (TDIM / BN);   // 32 * 16 * 8 = 4096
    mapper_gemm<<<grid, 256, 0, stream>>>(x, lang_ids, W, bias, out);
}